// Round 7
// baseline (241.048 us; speedup 1.0000x reference)
//
#include <hip/hip_runtime.h>
#include <hip/hip_bf16.h>

#define BSZ 4
#define SEQ 2048
#define DIM 1024

typedef __attribute__((ext_vector_type(8))) short bf16x8;
typedef __attribute__((ext_vector_type(4))) float floatx4;

__device__ __forceinline__ unsigned short f2bf(float x) {
  union { float f; unsigned int u; } v; v.f = x;
  unsigned int r = v.u + 0x7fffu + ((v.u >> 16) & 1u);
  return (unsigned short)(r >> 16);
}

template <typename T> __device__ __forceinline__ void store_c(T* p, float v);
template <> __device__ __forceinline__ void store_c<float>(float* p, float v) { *p = v; }
template <> __device__ __forceinline__ void store_c<unsigned short>(unsigned short* p, float v) { *p = f2bf(v); }

// ---------------- prep: cast E/Wq/Wk -> bf16 rows, zero rowsum, transpose+cast Wv ----------------
// blocks [0,8192): cast E (first 8 also zero Rsum)
// blocks [8192,9216): cast Wq rows   (NT layout needs no transpose)
// blocks [9216,10240): cast Wk rows
// blocks [10240,11264): transpose+cast Wv -> WtV (R6-proven body)
__global__ __launch_bounds__(256) void prep(const float* __restrict__ E,
                                            const float* __restrict__ Wq,
                                            const float* __restrict__ Wk,
                                            const float* __restrict__ Wv,
                                            unsigned short* __restrict__ Ebf,
                                            unsigned short* __restrict__ Wqbf,
                                            unsigned short* __restrict__ Wkbf,
                                            unsigned short* __restrict__ WtV,
                                            float* __restrict__ rsum) {
  __shared__ float tile[32][33];
  int b = blockIdx.x;
  int tid = threadIdx.x;
  if (b < 10240) {
    const float* src;
    unsigned short* dst;
    int base;
    if (b < 8192) {
      if (b < 8) {
        int j = b * 1024 + tid * 4;
        *(float4*)(rsum + j) = make_float4(0.f, 0.f, 0.f, 0.f);
      }
      src = E; dst = Ebf; base = b;
    } else if (b < 9216) {
      src = Wq; dst = Wqbf; base = b - 8192;
    } else {
      src = Wk; dst = Wkbf; base = b - 9216;
    }
    int i = (base * 256 + tid) * 4;
    float4 v = *(const float4*)(src + i);
    ushort4 o;
    o.x = f2bf(v.x); o.y = f2bf(v.y); o.z = f2bf(v.z); o.w = f2bf(v.w);
    *(ushort4*)(dst + i) = o;
  } else {
    int rb = b - 10240;                 // [0,1024)
    int bx = rb & 31, by = rb >> 5;
    int n0 = bx * 32, k0 = by * 32;
    int tx = tid & 31, ty = tid >> 5;   // 32 x 8
    for (int r = ty; r < 32; r += 8)
      tile[r][tx] = Wv[(size_t)(k0 + r) * DIM + n0 + tx];
    __syncthreads();
    for (int r = ty; r < 32; r += 8)
      WtV[(size_t)(n0 + r) * DIM + k0 + tx] = f2bf(tile[tx][r]);
  }
}

__device__ __forceinline__ void gload16(const unsigned short* g, unsigned short* l) {
  __builtin_amdgcn_global_load_lds(
      (const __attribute__((address_space(1))) unsigned int*)g,
      (__attribute__((address_space(3))) unsigned int*)l, 16, 0, 0);
}

// ---------------- R2-proven ring-4 core (128x256 tiles, 512 threads) — FROZEN ----------------
#define NT_PROJ 32  // K=1024 / BK=32

template <int BMt>
__device__ __forceinline__ void proj_core(
    const unsigned short* __restrict__ A,
    const unsigned short* __restrict__ Bm,
    unsigned short* __restrict__ C, int ldc, int m0, int n0,
    unsigned short* sAr, unsigned short* sBr) {
  constexpr int LPA = BMt / 128;
  constexpr int LPT = LPA + 2;
  constexpr int FR  = BMt / 32;
  constexpr int TA  = BMt * 32;
  constexpr int TB  = 256 * 32;

  const int tid = threadIdx.x;
  const int lane = tid & 63;
  const int wid = tid >> 6;
  const int wm = (wid >> 2) * (BMt / 2);
  const int wn = (wid & 3) * 64;
  const int lr = lane & 15, lq = lane >> 4;

  const int srow = tid >> 2;
  const int schunk = (tid & 3) ^ ((tid >> 3) & 3);
  const unsigned short* gA = A + (size_t)(m0 + srow) * DIM + schunk * 8;
  const unsigned short* gB = Bm + (size_t)(n0 + srow) * DIM + schunk * 8;
  unsigned short* lA = sAr + 16 * 32 * wid;
  unsigned short* lB = sBr + 16 * 32 * wid;
  const size_t swG = (size_t)128 * DIM;

#define STAGE_A(T) do { int rb_ = (T) & 3; \
    gload16(gA + (size_t)(T) * 32, lA + rb_ * TA); \
    if constexpr (LPA == 2) gload16(gA + (size_t)(T) * 32 + swG, lA + rb_ * TA + 4096); } while (0)
#define STAGE_B(T) do { int rb_ = (T) & 3; \
    gload16(gB + (size_t)(T) * 32,       lB + rb_ * TB); \
    gload16(gB + (size_t)(T) * 32 + swG, lB + rb_ * TB + 4096); } while (0)
#define ARD(rb_, rowv) (*(const bf16x8*)&sAr[(rb_) * TA + (rowv) * 32 + (lq ^ (((rowv) >> 1) & 3)) * 8])
#define BRD(rb_, rowv) (*(const bf16x8*)&sBr[(rb_) * TB + (rowv) * 32 + (lq ^ (((rowv) >> 1) & 3)) * 8])

  floatx4 acc[FR][4] = {};

  STAGE_A(0); STAGE_B(0);
  STAGE_A(1); STAGE_B(1);
  STAGE_A(2); STAGE_B(2);
  if constexpr (LPT == 4) asm volatile("s_waitcnt vmcnt(8)" ::: "memory");
  else                    asm volatile("s_waitcnt vmcnt(6)" ::: "memory");
  __builtin_amdgcn_s_barrier();

#pragma unroll 4
  for (int T = 0; T < NT_PROJ; ++T) {
    const int rb = T & 3;
    bf16x8 af[4], bfr[4];
#pragma unroll
    for (int j = 0; j < 4; ++j) bfr[j] = BRD(rb, wn + j * 16 + lr);
#pragma unroll
    for (int i = 0; i < 4; ++i) af[i] = ARD(rb, wm + i * 16 + lr);
    if (T + 3 < NT_PROJ) {
      STAGE_A(T + 3);
      if constexpr (BMt == 128) STAGE_B(T + 3);
    }
    __builtin_amdgcn_s_barrier();
    __builtin_amdgcn_s_setprio(1);
#pragma unroll
    for (int i = 0; i < 4; ++i)
#pragma unroll
      for (int j = 0; j < 4; ++j)
        acc[i][j] = __builtin_amdgcn_mfma_f32_16x16x32_bf16(af[i], bfr[j], acc[i][j], 0, 0, 0);
    __builtin_amdgcn_s_setprio(0);
    if constexpr (BMt == 256) {
      __builtin_amdgcn_s_barrier();
#pragma unroll
      for (int i = 0; i < 4; ++i) af[i] = ARD(rb, wm + 64 + i * 16 + lr);
      if (T + 3 < NT_PROJ) STAGE_B(T + 3);
      __builtin_amdgcn_s_barrier();
      __builtin_amdgcn_s_setprio(1);
#pragma unroll
      for (int i = 0; i < 4; ++i)
#pragma unroll
        for (int j = 0; j < 4; ++j)
          acc[4 + i][j] = __builtin_amdgcn_mfma_f32_16x16x32_bf16(af[i], bfr[j], acc[4 + i][j], 0, 0, 0);
      __builtin_amdgcn_s_setprio(0);
    }
    if (T < NT_PROJ - 3) {
      if constexpr (LPT == 4) asm volatile("s_waitcnt vmcnt(8)" ::: "memory");
      else                    asm volatile("s_waitcnt vmcnt(6)" ::: "memory");
    } else if (T == NT_PROJ - 3) {
      if constexpr (LPT == 4) asm volatile("s_waitcnt vmcnt(4)" ::: "memory");
      else                    asm volatile("s_waitcnt vmcnt(3)" ::: "memory");
    } else if (T == NT_PROJ - 2) {
      asm volatile("s_waitcnt vmcnt(0)" ::: "memory");
    }
    __builtin_amdgcn_s_barrier();
  }
#undef STAGE_A
#undef STAGE_B
#undef ARD
#undef BRD

#pragma unroll
  for (int i = 0; i < FR; ++i) {
    int rbase = m0 + wm + i * 16 + lq * 4;
#pragma unroll
    for (int j = 0; j < 4; ++j) {
      int col = n0 + wn + j * 16 + lr;
#pragma unroll
      for (int r = 0; r < 4; ++r)
        C[(size_t)(rbase + r) * ldc + col] = f2bf(acc[i][j][r]);
    }
  }
}

// ---------------- bulk1: Mt = Wk x Wq^T (32 blk) + Vt = WtV x Ebf^T (256 blk) ----------------
__global__ __launch_bounds__(512, 2) void bulk1(
    const unsigned short* __restrict__ Wkbf,
    const unsigned short* __restrict__ Wqbf,
    const unsigned short* __restrict__ Ebf,
    const unsigned short* __restrict__ WtV,
    unsigned short* __restrict__ Mt,
    unsigned short* __restrict__ Vt) {
  __shared__ __align__(16) unsigned short sA[16384];  // 32 KiB (ring 4 x 128x32)
  __shared__ __align__(16) unsigned short sB[32768];  // 64 KiB (ring 4 x 256x32)
  int x = blockIdx.x;
  if (x < 32) {
    // Mt[i][j] = sum_d Wk[i,d] Wq[j,d] : [1024][1024], 128x256 tiles (8x4)
    proj_core<128>(Wkbf, Wqbf, Mt, DIM, (x >> 2) * 128, (x & 3) * 256, sA, sB);
  } else {
    // Vt = WtV x Ebf^T : [1024][8192], 128x256 tiles (8x32)
    x -= 32;
    proj_core<128>(WtV, Ebf, Vt, BSZ * SEQ, (x >> 5) * 128, (x & 31) * 256, sA, sB);
  }
}

// ---------------- bulk2: EM = Ebf x Mt^T : [8192][1024], 128x256 tiles (64x4) ----------------
__global__ __launch_bounds__(512, 2) void bulk2(
    const unsigned short* __restrict__ Ebf,
    const unsigned short* __restrict__ Mt,
    unsigned short* __restrict__ EM) {
  __shared__ __align__(16) unsigned short sA[16384];
  __shared__ __align__(16) unsigned short sB[32768];
  int x = blockIdx.x;                   // [0,256): exactly one round on 256 CUs
  proj_core<128>(Ebf, Mt, EM, DIM, (x >> 2) * 128, (x & 3) * 256, sA, sB);
}

// =====================================================================
// scores / PV on the R2-proven ring-4 core (R5/R6-verified), 256-thread 128x128.
// MODE 1: scores = EM x Ebf^T -> exp numerator + rowsum atomics (tri grid).
// MODE 2: PV with causal Keff, complementary z-pairing (R6-verified).
// =====================================================================
template <typename OutT, int MODE>
__global__ __launch_bounds__(256, 2) void gemm_ring(
    const unsigned short* __restrict__ A, int lda, long long strideA,
    const unsigned short* __restrict__ B, int ldb, long long strideB,
    OutT* __restrict__ C, int ldc, long long strideC,
    int Kdim, float scale, float* __restrict__ rowsum) {
  int m0, n0;
  if constexpr (MODE == 1) {
    int t = blockIdx.x;           // packed lower-triangle decode
    int mt = 0;
    while (((mt + 1) * (mt + 2)) / 2 <= t) mt++;
    int nt = t - (mt * (mt + 1)) / 2;
    m0 = mt * 128; n0 = nt * 128;
  } else {
    int yy = ((blockIdx.z >> 1) & 1) ? blockIdx.y : (gridDim.y - 1 - blockIdx.y);
    m0 = yy * 128;
    n0 = blockIdx.x * 128;
  }
  const int Keff = (MODE == 2) ? min(Kdim, m0 + 128) : Kdim;
  const int NT = Keff >> 5;
  A += (long long)blockIdx.z * strideA;
  B += (long long)blockIdx.z * strideB;
  C += (long long)blockIdx.z * strideC;
  rowsum += (size_t)blockIdx.z * SEQ;

  __shared__ __align__(16) unsigned short sA[4 * 4096];  // 32 KiB
  __shared__ __align__(16) unsigned short sB[4 * 4096];  // 32 KiB

  const int tid = threadIdx.x;
  const int lane = tid & 63;
  const int wid = tid >> 6;
  const int wm = (wid >> 1) * 64, wn = (wid & 1) * 64;
  const int lr = lane & 15, lq = lane >> 4;

  const int schunk = (tid & 3) ^ ((tid >> 3) & 3);
  const unsigned short* gA = A + (size_t)(m0 + (tid >> 2)) * lda + schunk * 8;
  const unsigned short* gB = B + (size_t)(n0 + (tid >> 2)) * ldb + schunk * 8;
  unsigned short* lA = sA + wid * 512;
  unsigned short* lB = sB + wid * 512;
  const size_t sGA = (size_t)64 * lda, sGB = (size_t)64 * ldb;

#define RSTAGE(T) do { int rb_ = (T) & 3; \
    gload16(gA + (size_t)(T) * 32,       lA + rb_ * 4096); \
    gload16(gA + (size_t)(T) * 32 + sGA, lA + rb_ * 4096 + 2048); \
    gload16(gB + (size_t)(T) * 32,       lB + rb_ * 4096); \
    gload16(gB + (size_t)(T) * 32 + sGB, lB + rb_ * 4096 + 2048); } while (0)
#define RARD(rb_, rowv) (*(const bf16x8*)&sA[(rb_) * 4096 + (rowv) * 32 + (lq ^ (((rowv) >> 1) & 3)) * 8])
#define RBRD(rb_, rowv) (*(const bf16x8*)&sB[(rb_) * 4096 + (rowv) * 32 + (lq ^ (((rowv) >> 1) & 3)) * 8])

  floatx4 acc[4][4] = {};

  RSTAGE(0); RSTAGE(1); RSTAGE(2);
  asm volatile("s_waitcnt vmcnt(8)" ::: "memory");
  __builtin_amdgcn_s_barrier();

  for (int T = 0; T < NT; ++T) {
    const int rb = T & 3;
    bf16x8 af[4], bfr[4];
#pragma unroll
    for (int j = 0; j < 4; ++j) bfr[j] = RBRD(rb, wn + j * 16 + lr);
#pragma unroll
    for (int i = 0; i < 4; ++i) af[i] = RARD(rb, wm + i * 16 + lr);
    if (T + 3 < NT) RSTAGE(T + 3);
    __builtin_amdgcn_s_barrier();
    __builtin_amdgcn_s_setprio(1);
#pragma unroll
    for (int i = 0; i < 4; ++i)
#pragma unroll
      for (int j = 0; j < 4; ++j)
        acc[i][j] = __builtin_amdgcn_mfma_f32_16x16x32_bf16(af[i], bfr[j], acc[i][j], 0, 0, 0);
    __builtin_amdgcn_s_setprio(0);
    if (T < NT - 3)       asm volatile("s_waitcnt vmcnt(8)" ::: "memory");
    else if (T == NT - 3) asm volatile("s_waitcnt vmcnt(4)" ::: "memory");
    else if (T == NT - 2) asm volatile("s_waitcnt vmcnt(0)" ::: "memory");
    __builtin_amdgcn_s_barrier();
  }
#undef RSTAGE
#undef RARD
#undef RBRD

  if constexpr (MODE == 1) {
#pragma unroll
    for (int i = 0; i < 4; i++) {
      int rbase = m0 + wm + i * 16 + lq * 4;
      float s0 = 0.f, s1 = 0.f, s2 = 0.f, s3 = 0.f;
#pragma unroll
      for (int j = 0; j < 4; j++) {
        int col = n0 + wn + j * 16 + lr;
        float e0 = (col <= rbase + 0) ? __expf(acc[i][j][0] * scale) : 0.0f;
        float e1 = (col <= rbase + 1) ? __expf(acc[i][j][1] * scale) : 0.0f;
        float e2 = (col <= rbase + 2) ? __expf(acc[i][j][2] * scale) : 0.0f;
        float e3 = (col <= rbase + 3) ? __expf(acc[i][j][3] * scale) : 0.0f;
        store_c(&C[(size_t)(rbase + 0) * ldc + col], e0);
        store_c(&C[(size_t)(rbase + 1) * ldc + col], e1);
        store_c(&C[(size_t)(rbase + 2) * ldc + col], e2);
        store_c(&C[(size_t)(rbase + 3) * ldc + col], e3);
        s0 += e0; s1 += e1; s2 += e2; s3 += e3;
      }
#pragma unroll
      for (int m = 1; m < 16; m <<= 1) {
        s0 += __shfl_xor(s0, m, 64);
        s1 += __shfl_xor(s1, m, 64);
        s2 += __shfl_xor(s2, m, 64);
        s3 += __shfl_xor(s3, m, 64);
      }
      if (lr == 0) {
        atomicAdd(&rowsum[rbase + 0], s0);
        atomicAdd(&rowsum[rbase + 1], s1);
        atomicAdd(&rowsum[rbase + 2], s2);
        atomicAdd(&rowsum[rbase + 3], s3);
      }
    }
  } else {
#pragma unroll
    for (int i = 0; i < 4; i++) {
      int rbase = m0 + wm + i * 16 + lq * 4;
      float i0 = 1.0f / rowsum[rbase + 0];
      float i1 = 1.0f / rowsum[rbase + 1];
      float i2 = 1.0f / rowsum[rbase + 2];
      float i3 = 1.0f / rowsum[rbase + 3];
#pragma unroll
      for (int j = 0; j < 4; j++) {
        int col = n0 + wn + j * 16 + lr;
        store_c(&C[(size_t)(rbase + 0) * ldc + col], acc[i][j][0] * i0);
        store_c(&C[(size_t)(rbase + 1) * ldc + col], acc[i][j][1] * i1);
        store_c(&C[(size_t)(rbase + 2) * ldc + col], acc[i][j][2] * i2);
        store_c(&C[(size_t)(rbase + 3) * ldc + col], acc[i][j][3] * i3);
      }
    }
  }
}

extern "C" void kernel_launch(void* const* d_in, const int* in_sizes, int n_in,
                              void* d_out, int out_size, void* d_ws, size_t ws_size,
                              hipStream_t stream) {
  const float* E  = (const float*)d_in[0];
  const float* Wq = (const float*)d_in[1];
  const float* Wk = (const float*)d_in[2];
  const float* Wv = (const float*)d_in[3];
  float* out = (float*)d_out;

  char* ws = (char*)d_ws;
  size_t off = 0;
  auto alloc = [&](size_t bytes) {
    void* p = ws + off;
    off += (bytes + 255) & ~(size_t)255;
    return p;
  };
  const size_t M_ALL = (size_t)BSZ * SEQ;
  unsigned short* Ebf  = (unsigned short*)alloc(M_ALL * DIM * 2);
  unsigned short* Wqbf = (unsigned short*)alloc((size_t)DIM * DIM * 2);
  unsigned short* Wkbf = (unsigned short*)alloc((size_t)DIM * DIM * 2);
  unsigned short* WtV  = (unsigned short*)alloc((size_t)DIM * DIM * 2);
  unsigned short* Mt   = (unsigned short*)alloc((size_t)DIM * DIM * 2);
  unsigned short* EM   = (unsigned short*)alloc(M_ALL * DIM * 2);
  unsigned short* Vt   = (unsigned short*)alloc((size_t)DIM * M_ALL * 2);
  unsigned short* ExpS = (unsigned short*)alloc((size_t)BSZ * SEQ * SEQ * 2);
  float*          Rsum = (float*)alloc((size_t)BSZ * SEQ * 4);

  // casts + Wv transpose + Rsum zero (one dispatch)
  prep<<<dim3(11264), dim3(256), 0, stream>>>(E, Wq, Wk, Wv, Ebf, Wqbf, Wkbf, WtV, Rsum);

  // Mt = Wk x Wq^T (32 blk) + Vt = WtV x Ebf^T (256 blk)
  bulk1<<<dim3(288), dim3(512), 0, stream>>>(Wkbf, Wqbf, Ebf, WtV, Mt, Vt);

  // EM = Ebf x Mt^T (256 blk = one full round)
  bulk2<<<dim3(256), dim3(512), 0, stream>>>(Ebf, Mt, EM);

  // scores = EM x Ebf^T -> exp numerators (bf16) + rowsum atomics; tri grid
  gemm_ring<unsigned short, 1><<<dim3(136, 1, BSZ), dim3(256), 0, stream>>>(
      EM, DIM, (long long)SEQ * DIM,
      Ebf, DIM, (long long)SEQ * DIM,
      ExpS, SEQ, (long long)SEQ * SEQ,
      DIM, 0.03125f /* 1/sqrt(1024) */, Rsum);

  // PV: out[q][d] = (sum_k expS[q][k] * Vt[d][k]) / rowsum[q]
  gemm_ring<float, 2><<<dim3(8, 16, BSZ), dim3(256), 0, stream>>>(
      ExpS, SEQ, (long long)SEQ * SEQ,
      Vt, (int)M_ALL, (long long)SEQ,
      out, DIM, (long long)SEQ * DIM,
      SEQ, 1.0f, Rsum);
}